// Round 8
// baseline (38.774 us; speedup 1.0000x reference)
//
#include <hip/hip_runtime.h>

#define DLEN     4096
#define TPB      256           // 4 waves per block, one row per block
#define NWAVE    4
#define EPT      16            // elements per lane (4 float4 chunks)
#define CAPW     1024          // worst-case survivors per wave
#define NEWT_MAX  8            // Newton cap, register fast path (typical exit ~5)
#define NEWT_MAXG 10           // Newton cap, LDS path
#define NBISECT  31            // bisection evals (general-alpha path)
#define FEPS     1e-4f         // |sum-1| tolerance: tau err ~ FEPS/(2*s1) ~ 4e-6

typedef float floatx4 __attribute__((ext_vector_type(4)));  // native vec for nt-store

__device__ __forceinline__ int prefix_cnt(unsigned long long bm) {
    // popcount of bm over lanes strictly below this lane
    return __builtin_amdgcn_mbcnt_hi((unsigned)(bm >> 32),
           __builtin_amdgcn_mbcnt_lo((unsigned)bm, 0u));
}

__global__ __launch_bounds__(TPB, 8)
void entmax_kernel(const float* __restrict__ scores,
                   const int* __restrict__ mask,
                   const float* __restrict__ alpha_ptr,
                   float* __restrict__ out)
{
    __shared__ float sv[NWAVE][CAPW + 64];   // per-wave compacted survivors + pad
    __shared__ int   wcnt[NWAVE];
    __shared__ float wred[NWAVE];

    const int tid  = threadIdx.x;
    const int w    = tid >> 6;
    const int lane = tid & 63;
    const int row  = blockIdx.x;

    const float NEG = -1e30f;

    const float alpha = fmaxf(alpha_ptr[0], 1.001f);
    const float am1   = alpha - 1.0f;
    const float expo  = 1.0f / am1;
    const bool  sq    = (expo == 2.0f);      // alpha == 1.5 exact fast path

    const size_t base = (size_t)row * DLEN;
    const float* srow = scores + base;
    const int*   mrow = mask + base;

    // ---- load 16 elems/lane into registers, apply mask + scale, wave max ----
    float xs[EPT];
    float wmax = NEG;
#pragma unroll
    for (int c = 0; c < 4; ++c) {
        const int idx = c * (TPB * 4) + tid * 4;
        const float4 s = *reinterpret_cast<const float4*>(srow + idx);
        const int4   m = *reinterpret_cast<const int4*>(mrow + idx);
        const float x0 = m.x ? s.x * am1 : NEG;
        const float x1 = m.y ? s.y * am1 : NEG;
        const float x2 = m.z ? s.z * am1 : NEG;
        const float x3 = m.w ? s.w * am1 : NEG;
        xs[c*4+0] = x0; xs[c*4+1] = x1; xs[c*4+2] = x2; xs[c*4+3] = x3;
        wmax = fmaxf(wmax, fmaxf(fmaxf(x0, x1), fmaxf(x2, x3)));
    }
#pragma unroll
    for (int off = 32; off; off >>= 1)
        wmax = fmaxf(wmax, __shfl_xor(wmax, off));
    if (lane == 0) wred[w] = wmax;
    __syncthreads();
    const float rmax = fmaxf(fmaxf(wred[0], wred[1]), fmaxf(wred[2], wred[3]));

    // Every tau ever evaluated is >= tau_lo0 = rmax - 1 (bisection lower bound;
    // Newton from below only increases): x <= tau_lo0 contributes 0 always.
    // Global threshold keeps survivors/wave ~51 -> register fast path ~90%.
    const float tau_lo0 = rmax - 1.0f;

    // ---- per-wave ballot stream-compaction of survivors into LDS ----
    int cnt = 0;
#pragma unroll
    for (int e = 0; e < EPT; ++e) {
        const bool pred = xs[e] > tau_lo0;
        const unsigned long long bm = __ballot(pred);
        if (pred)
            sv[w][cnt + prefix_cnt(bm)] = xs[e];
        cnt += __popcll(bm);
    }
    sv[w][cnt + lane] = NEG;                 // pad one full chunk
    if (lane == 0) wcnt[w] = cnt;
    __syncthreads();                         // sv + wcnt visible to all waves

    int nct[NWAVE];
    bool fast = true;
#pragma unroll
    for (int ws = 0; ws < NWAVE; ++ws) {
        const int c4 = wcnt[ws];
        nct[ws] = (c4 + 63) >> 6;
        fast = fast && (c4 <= 64);
    }

    float tau_m = tau_lo0;
    float sum_m = 0.0f;

    if (sq) {
        if (fast) {
            // ---- hot path: <=64 survivors/wave -> 4 register values/lane,
            //      Newton with no LDS traffic, wave-uniform early exit ----
            const float r0 = sv[0][lane];
            const float r1 = sv[1][lane];
            const float r2 = sv[2][lane];
            const float r3 = sv[3][lane];
#pragma unroll 1
            for (int it = 0; it < NEWT_MAX; ++it) {
                const float z0 = fmaxf(r0 - tau_m, 0.f);
                const float z1 = fmaxf(r1 - tau_m, 0.f);
                const float z2 = fmaxf(r2 - tau_m, 0.f);
                const float z3 = fmaxf(r3 - tau_m, 0.f);
                float s2 = z0 * z0;
                s2 = fmaf(z1, z1, s2);
                s2 = fmaf(z2, z2, s2);
                s2 = fmaf(z3, z3, s2);
                float s1 = (z0 + z1) + (z2 + z3);
#pragma unroll
                for (int off = 32; off; off >>= 1) {
                    s2 += __shfl_xor(s2, off);
                    s1 += __shfl_xor(s1, off);
                }
                sum_m = s2;
                const float f = s2 - 1.0f;
                if (!(f > FEPS) || !(s1 > 0.f)) break;     // converged from below
                if (it < NEWT_MAX - 1)
                    tau_m += f * 0.5f / s1;                // keep (tau,sum) consistent
            }
        } else {
            // ---- general survivor count: Newton over LDS segments ----
#pragma unroll 1
            for (int it = 0; it < NEWT_MAXG; ++it) {
                float s2 = 0.f, s1 = 0.f;
                for (int ws = 0; ws < NWAVE; ++ws) {
                    const int n = nct[ws];
                    for (int c = 0; c < n; ++c) {
                        const float z = fmaxf(sv[ws][c * 64 + lane] - tau_m, 0.f);
                        s2 = fmaf(z, z, s2);
                        s1 += z;
                    }
                }
#pragma unroll
                for (int off = 32; off; off >>= 1) {
                    s2 += __shfl_xor(s2, off);
                    s1 += __shfl_xor(s1, off);
                }
                sum_m = s2;
                const float f = s2 - 1.0f;
                if (!(f > FEPS) || !(s1 > 0.f)) break;
                if (it < NEWT_MAXG - 1)
                    tau_m += f * 0.5f / s1;
            }
        }
    } else {
        // ---- general alpha: reference-faithful bisection, redundant scan ----
        const float tau_hi = rmax - exp2f(-12.0f * am1);  // (1/4096)^(alpha-1)

        auto rsum = [&](float tau) -> float {
            float s = 0.f;
            for (int ws = 0; ws < NWAVE; ++ws) {
                const int n = nct[ws];
                for (int c = 0; c < n; ++c) {
                    const float z = sv[ws][c * 64 + lane] - tau;
                    s += (z > 0.f) ? powf(z, expo) : 0.f;
                }
            }
#pragma unroll
            for (int off = 32; off; off >>= 1) s += __shfl_xor(s, off);
            return s;
        };

        float tau_lo = tau_lo0;
        const float f_lo = rsum(tau_lo0) - 1.0f;
        float dm = tau_hi - tau_lo0;
#pragma unroll 1
        for (int it = 0; it < NBISECT; ++it) {
            dm *= 0.5f;
            tau_m = tau_lo + dm;
            sum_m = rsum(tau_m);
            const float f_m = sum_m - 1.0f;
            tau_lo = (f_m * f_lo >= 0.0f) ? tau_m : tau_lo;
        }
    }

    // ---- epilogue: p = clip(x - tau_m, 0)^exp / sum_m, from registers ----
    const float inv = 1.0f / sum_m;
#pragma unroll
    for (int c = 0; c < 4; ++c) {
        const int idx = c * (TPB * 4) + tid * 4;
        floatx4 o;
        if (sq) {
            float z;
            z = fmaxf(xs[c*4+0] - tau_m, 0.f); o.x = z * z * inv;
            z = fmaxf(xs[c*4+1] - tau_m, 0.f); o.y = z * z * inv;
            z = fmaxf(xs[c*4+2] - tau_m, 0.f); o.z = z * z * inv;
            z = fmaxf(xs[c*4+3] - tau_m, 0.f); o.w = z * z * inv;
        } else {
            float z;
            z = xs[c*4+0] - tau_m; o.x = (z > 0.f) ? powf(z, expo) * inv : 0.f;
            z = xs[c*4+1] - tau_m; o.y = (z > 0.f) ? powf(z, expo) * inv : 0.f;
            z = xs[c*4+2] - tau_m; o.z = (z > 0.f) ? powf(z, expo) * inv : 0.f;
            z = xs[c*4+3] - tau_m; o.w = (z > 0.f) ? powf(z, expo) * inv : 0.f;
        }
        __builtin_nontemporal_store(o, reinterpret_cast<floatx4*>(out + base + idx));
    }
}

extern "C" void kernel_launch(void* const* d_in, const int* in_sizes, int n_in,
                              void* d_out, int out_size, void* d_ws, size_t ws_size,
                              hipStream_t stream) {
    const float* scores = (const float*)d_in[0];
    const int*   mask   = (const int*)d_in[1];
    const float* alpha  = (const float*)d_in[2];
    float*       out    = (float*)d_out;
    const int rows = in_sizes[0] / DLEN;
    entmax_kernel<<<rows, TPB, 0, stream>>>(scores, mask, alpha, out);
}

// Round 9
// 38.557 us; speedup vs baseline: 1.0056x; 1.0056x over previous
//
#include <hip/hip_runtime.h>

#define DLEN     4096
#define TPB      256           // 4 waves per block, one row per block
#define NWAVE    4
#define EPT      16            // elements per lane (4 float4 chunks)
#define CAPW     1024          // worst-case survivors per wave
#define AS_MAX    6            // active-set iteration cap (typical exit ~3)
#define NBISECT  31            // bisection evals (general-alpha path)

typedef float floatx4 __attribute__((ext_vector_type(4)));  // native vec for nt-store

__device__ __forceinline__ int prefix_cnt(unsigned long long bm) {
    return __builtin_amdgcn_mbcnt_hi((unsigned)(bm >> 32),
           __builtin_amdgcn_mbcnt_lo((unsigned)bm, 0u));
}

__global__ __launch_bounds__(TPB, 8)
void entmax_kernel(const float* __restrict__ scores,
                   const int* __restrict__ mask,
                   const float* __restrict__ alpha_ptr,
                   float* __restrict__ out)
{
    __shared__ float sv[NWAVE][CAPW + 64];   // per-wave compacted survivors + pad
    __shared__ int   wcnt[NWAVE];
    __shared__ float wred[NWAVE];

    const int tid  = threadIdx.x;
    const int w    = tid >> 6;
    const int lane = tid & 63;
    const int row  = blockIdx.x;

    const float NEG = -1e30f;

    const float alpha = fmaxf(alpha_ptr[0], 1.001f);
    const float am1   = alpha - 1.0f;
    const float expo  = 1.0f / am1;
    const bool  sq    = (expo == 2.0f);      // alpha == 1.5 exact fast path

    const size_t base = (size_t)row * DLEN;
    const float* srow = scores + base;
    const int*   mrow = mask + base;

    // ---- load 16 elems/lane into registers, apply mask + scale, wave max ----
    float xs[EPT];
    float wmax = NEG;
#pragma unroll
    for (int c = 0; c < 4; ++c) {
        const int idx = c * (TPB * 4) + tid * 4;
        const float4 s = *reinterpret_cast<const float4*>(srow + idx);
        const int4   m = *reinterpret_cast<const int4*>(mrow + idx);
        const float x0 = m.x ? s.x * am1 : NEG;
        const float x1 = m.y ? s.y * am1 : NEG;
        const float x2 = m.z ? s.z * am1 : NEG;
        const float x3 = m.w ? s.w * am1 : NEG;
        xs[c*4+0] = x0; xs[c*4+1] = x1; xs[c*4+2] = x2; xs[c*4+3] = x3;
        wmax = fmaxf(wmax, fmaxf(fmaxf(x0, x1), fmaxf(x2, x3)));
    }
#pragma unroll
    for (int off = 32; off; off >>= 1)
        wmax = fmaxf(wmax, __shfl_xor(wmax, off));
    if (lane == 0) wred[w] = wmax;
    __syncthreads();
    const float rmax = fmaxf(fmaxf(wred[0], wred[1]), fmaxf(wred[2], wred[3]));

    // Every tau ever evaluated is >= tau_lo0 = rmax - 1 (f(tau_lo0) >= 1 since
    // the max element alone contributes 1): x <= tau_lo0 contributes 0 always.
    const float tau_lo0 = rmax - 1.0f;

    // ---- per-wave ballot stream-compaction of survivors into LDS ----
    int cnt = 0;
#pragma unroll
    for (int e = 0; e < EPT; ++e) {
        const bool pred = xs[e] > tau_lo0;
        const unsigned long long bm = __ballot(pred);
        if (pred)
            sv[w][cnt + prefix_cnt(bm)] = xs[e];
        cnt += __popcll(bm);
    }
    sv[w][cnt + lane] = NEG;                 // pad one full chunk
    if (lane == 0) wcnt[w] = cnt;
    __syncthreads();                         // sv + wcnt visible to all waves

    int nct[NWAVE];
    bool fast = true;
#pragma unroll
    for (int ws = 0; ws < NWAVE; ++ws) {
        const int c4 = wcnt[ws];
        nct[ws] = (c4 + 63) >> 6;
        fast = fast && (c4 <= 64);
    }

    float tau_m = tau_lo0;
    float sum_m = 1.0f;

    if (sq) {
        // ---- exact active-set solver: given A={x>tau}, the exact threshold
        //      for that set solves k*d^2 - 2*S1'*d + (S2'-1) = 0 (shifted by
        //      tau). When the evaluated k repeats, the previous solve used the
        //      correct set -> f(tau)=1 exactly; S2' is the true normalizer. ----
        float k_prev = -1.0f;
        if (fast) {
            const float r0 = sv[0][lane];
            const float r1 = sv[1][lane];
            const float r2 = sv[2][lane];
            const float r3 = sv[3][lane];
#pragma unroll 1
            for (int it = 0; it < AS_MAX; ++it) {
                const float z0 = fmaxf(r0 - tau_m, 0.f);
                const float z1 = fmaxf(r1 - tau_m, 0.f);
                const float z2 = fmaxf(r2 - tau_m, 0.f);
                const float z3 = fmaxf(r3 - tau_m, 0.f);
                float s2 = z0 * z0;
                s2 = fmaf(z1, z1, s2);
                s2 = fmaf(z2, z2, s2);
                s2 = fmaf(z3, z3, s2);
                float s1 = (z0 + z1) + (z2 + z3);
                float k  = ((z0 > 0.f ? 1.f : 0.f) + (z1 > 0.f ? 1.f : 0.f))
                         + ((z2 > 0.f ? 1.f : 0.f) + (z3 > 0.f ? 1.f : 0.f));
#pragma unroll
                for (int off = 32; off; off >>= 1) {
                    s2 += __shfl_xor(s2, off);
                    s1 += __shfl_xor(s1, off);
                    k  += __shfl_xor(k,  off);
                }
                sum_m = s2;
                if (k == k_prev || k <= 0.f) break;        // set stable -> exact
                k_prev = k;
                const float disc = fmaxf(fmaf(-k, s2 - 1.0f, s1 * s1), 0.f);
                tau_m += (s1 - sqrtf(disc)) / k;
            }
        } else {
#pragma unroll 1
            for (int it = 0; it < AS_MAX; ++it) {
                float s2 = 0.f, s1 = 0.f, k = 0.f;
                for (int ws = 0; ws < NWAVE; ++ws) {
                    const int n = nct[ws];
                    for (int c = 0; c < n; ++c) {
                        const float z = fmaxf(sv[ws][c * 64 + lane] - tau_m, 0.f);
                        s2 = fmaf(z, z, s2);
                        s1 += z;
                        k  += (z > 0.f) ? 1.f : 0.f;
                    }
                }
#pragma unroll
                for (int off = 32; off; off >>= 1) {
                    s2 += __shfl_xor(s2, off);
                    s1 += __shfl_xor(s1, off);
                    k  += __shfl_xor(k,  off);
                }
                sum_m = s2;
                if (k == k_prev || k <= 0.f) break;
                k_prev = k;
                const float disc = fmaxf(fmaf(-k, s2 - 1.0f, s1 * s1), 0.f);
                tau_m += (s1 - sqrtf(disc)) / k;
            }
        }
    } else {
        // ---- general alpha: reference-faithful bisection, redundant scan ----
        const float tau_hi = rmax - exp2f(-12.0f * am1);  // (1/4096)^(alpha-1)

        auto rsum = [&](float tau) -> float {
            float s = 0.f;
            for (int ws = 0; ws < NWAVE; ++ws) {
                const int n = nct[ws];
                for (int c = 0; c < n; ++c) {
                    const float z = sv[ws][c * 64 + lane] - tau;
                    s += (z > 0.f) ? powf(z, expo) : 0.f;
                }
            }
#pragma unroll
            for (int off = 32; off; off >>= 1) s += __shfl_xor(s, off);
            return s;
        };

        float tau_lo = tau_lo0;
        const float f_lo = rsum(tau_lo0) - 1.0f;
        float dm = tau_hi - tau_lo0;
#pragma unroll 1
        for (int it = 0; it < NBISECT; ++it) {
            dm *= 0.5f;
            tau_m = tau_lo + dm;
            sum_m = rsum(tau_m);
            const float f_m = sum_m - 1.0f;
            tau_lo = (f_m * f_lo >= 0.0f) ? tau_m : tau_lo;
        }
    }

    // ---- epilogue: p = clip(x - tau_m, 0)^exp / sum_m, from registers ----
    const float inv = 1.0f / sum_m;
#pragma unroll
    for (int c = 0; c < 4; ++c) {
        const int idx = c * (TPB * 4) + tid * 4;
        floatx4 o;
        if (sq) {
            float z;
            z = fmaxf(xs[c*4+0] - tau_m, 0.f); o.x = z * z * inv;
            z = fmaxf(xs[c*4+1] - tau_m, 0.f); o.y = z * z * inv;
            z = fmaxf(xs[c*4+2] - tau_m, 0.f); o.z = z * z * inv;
            z = fmaxf(xs[c*4+3] - tau_m, 0.f); o.w = z * z * inv;
        } else {
            float z;
            z = xs[c*4+0] - tau_m; o.x = (z > 0.f) ? powf(z, expo) * inv : 0.f;
            z = xs[c*4+1] - tau_m; o.y = (z > 0.f) ? powf(z, expo) * inv : 0.f;
            z = xs[c*4+2] - tau_m; o.z = (z > 0.f) ? powf(z, expo) * inv : 0.f;
            z = xs[c*4+3] - tau_m; o.w = (z > 0.f) ? powf(z, expo) * inv : 0.f;
        }
        __builtin_nontemporal_store(o, reinterpret_cast<floatx4*>(out + base + idx));
    }
}

extern "C" void kernel_launch(void* const* d_in, const int* in_sizes, int n_in,
                              void* d_out, int out_size, void* d_ws, size_t ws_size,
                              hipStream_t stream) {
    const float* scores = (const float*)d_in[0];
    const int*   mask   = (const int*)d_in[1];
    const float* alpha  = (const float*)d_in[2];
    float*       out    = (float*)d_out;
    const int rows = in_sizes[0] / DLEN;
    entmax_kernel<<<rows, TPB, 0, stream>>>(scores, mask, alpha, out);
}